// Round 1
// baseline (5729.547 us; speedup 1.0000x reference)
//
#include <hip/hip_runtime.h>

#define NN 100000
#define NE 1600000
#define D  128
#define R  5
#define L  3

// ---------------------------------------------------------------------------
// Per-(dst,relation) in-degree counts -> inverse (mean with empty->0 handled
// naturally: empty segments simply receive no scatter contributions).
// ---------------------------------------------------------------------------
__global__ __launch_bounds__(256) void count_kernel(const int* __restrict__ dst,
                                                    const int* __restrict__ et,
                                                    int* __restrict__ cnt) {
    int e = blockIdx.x * 256 + threadIdx.x;
    if (e < NE) atomicAdd(&cnt[dst[e] * R + et[e]], 1);
}

__global__ __launch_bounds__(256) void inv_kernel(const int* __restrict__ cnt,
                                                  float* __restrict__ inv) {
    int i = blockIdx.x * 256 + threadIdx.x;
    if (i < NN * R) {
        int c = cnt[i];
        inv[i] = 1.0f / (float)(c > 0 ? c : 1);
    }
}

// ---------------------------------------------------------------------------
// fp32 GEMM: C[N x 128] = act(A)[N x 128] @ B[128 x 128] (+ bias)
// Tile: 64 rows x 128 cols per 256-thread block.
// LDS: full B (64 KB) + 32-deep A k-chunk transposed (8.5 KB) -> 2 blocks/CU.
// Each thread: 4 rows x 8 cols outer product, float4 LDS reads.
// ---------------------------------------------------------------------------
template <bool RELU, bool BIAS>
__global__ __launch_bounds__(256) void gemm_kernel(const float* __restrict__ A,
                                                   const float* __restrict__ B,
                                                   const float* __restrict__ bias,
                                                   float* __restrict__ C) {
    __shared__ float Bs[128][128];   // Bs[k][col]
    __shared__ float As[32][68];     // As[k][row], +4 pad keeps 16B alignment

    const int tid  = threadIdx.x;
    const int row0 = blockIdx.x * 64;
    const int rgrp = (tid & 15) * 4;   // row offset within tile
    const int cgrp = (tid >> 4) * 8;   // col offset

    // stage all of B (16384 floats / 256 thr = 16 float4 each)
    {
        const float4* Bv  = (const float4*)B;
        float4*       Bsv = (float4*)&Bs[0][0];
#pragma unroll
        for (int i = 0; i < 16; ++i) Bsv[tid + i * 256] = Bv[tid + i * 256];
    }

    float acc[4][8];
#pragma unroll
    for (int i = 0; i < 4; ++i)
#pragma unroll
        for (int j = 0; j < 8; ++j) acc[i][j] = 0.0f;

#pragma unroll 1
    for (int kc = 0; kc < 128; kc += 32) {
        __syncthreads();  // covers Bs stage (first iter) and As reuse (later)
        // stage As[k][row]: 64 rows x 32 k = 2048 floats, 8 per thread
#pragma unroll
        for (int i = 0; i < 8; ++i) {
            int idx = tid + i * 256;
            int k = idx & 31, r = idx >> 5;
            int grow = row0 + r;
            float v = (grow < NN) ? A[(size_t)grow * D + kc + k] : 0.0f;
            if (RELU) v = fmaxf(v, 0.0f);
            As[k][r] = v;
        }
        __syncthreads();

#pragma unroll
        for (int k = 0; k < 32; ++k) {
            const float4 a  = *(const float4*)&As[k][rgrp];
            const float4 b0 = *(const float4*)&Bs[kc + k][cgrp];
            const float4 b1 = *(const float4*)&Bs[kc + k][cgrp + 4];
            const float av[4] = {a.x, a.y, a.z, a.w};
            const float bv[8] = {b0.x, b0.y, b0.z, b0.w, b1.x, b1.y, b1.z, b1.w};
#pragma unroll
            for (int i = 0; i < 4; ++i)
#pragma unroll
                for (int j = 0; j < 8; ++j) acc[i][j] += av[i] * bv[j];
        }
    }

    // epilogue
#pragma unroll
    for (int i = 0; i < 4; ++i) {
        int grow = row0 + rgrp + i;
        if (grow < NN) {
#pragma unroll
            for (int j = 0; j < 8; j += 4) {
                float4 v = make_float4(acc[i][j], acc[i][j + 1], acc[i][j + 2], acc[i][j + 3]);
                if (BIAS) {
                    v.x += bias[cgrp + j];
                    v.y += bias[cgrp + j + 1];
                    v.z += bias[cgrp + j + 2];
                    v.w += bias[cgrp + j + 3];
                }
                *(float4*)&C[(size_t)grow * D + cgrp + j] = v;
            }
        }
    }
}

// ---------------------------------------------------------------------------
// Scatter for relation `rel`: out[dst] += Y[src] * inv[dst*R+rel]
// One wave (64 lanes) per edge; 2 floats / lane -> 128 floats.
// ---------------------------------------------------------------------------
__global__ __launch_bounds__(256) void scatter_kernel(const float* __restrict__ Y,
                                                      const int* __restrict__ src,
                                                      const int* __restrict__ dst,
                                                      const int* __restrict__ et,
                                                      const float* __restrict__ inv,
                                                      float* __restrict__ out,
                                                      int rel) {
    int e = blockIdx.x * 4 + (threadIdx.x >> 6);
    if (e >= NE) return;
    int t = et[e];
    if (t != rel) return;
    int s = src[e], d = dst[e];
    float scale = inv[d * R + t];
    int lane = threadIdx.x & 63;
    float2 y = *(const float2*)&Y[(size_t)s * D + lane * 2];
    float* o = &out[(size_t)d * D + lane * 2];
    atomicAdd(o,     y.x * scale);
    atomicAdd(o + 1, y.y * scale);
}

// ---------------------------------------------------------------------------
extern "C" void kernel_launch(void* const* d_in, const int* in_sizes, int n_in,
                              void* d_out, int out_size, void* d_ws, size_t ws_size,
                              hipStream_t stream) {
    const float* x      = (const float*)d_in[0];
    const int*   eidx   = (const int*)d_in[1];
    const int*   etyp   = (const int*)d_in[2];
    const float* W      = (const float*)d_in[3];   // [L][R][D][D]
    const float* roots  = (const float*)d_in[4];   // [L][D][D]
    const float* biases = (const float*)d_in[5];   // [L][D]
    float*       out    = (float*)d_out;

    const int* src = eidx;
    const int* dst = eidx + NE;

    float* ws   = (float*)d_ws;
    float* bufA = ws;                            // N*D
    float* bufB = bufA + (size_t)NN * D;         // N*D
    float* Ybuf = bufB + (size_t)NN * D;         // N*D
    float* invp = Ybuf + (size_t)NN * D;         // N*R
    int*   cnt  = (int*)(invp + (size_t)NN * R); // N*R

    hipMemsetAsync(cnt, 0, sizeof(int) * (size_t)NN * R, stream);
    count_kernel<<<(NE + 255) / 256, 256, 0, stream>>>(dst, etyp, cnt);
    inv_kernel<<<(NN * R + 255) / 256, 256, 0, stream>>>(cnt, invp);

    const dim3 ggrid((NN + 63) / 64);
    const dim3 sgrid((NE + 3) / 4);

    const float* h = x;
    for (int l = 0; l < L; ++l) {
        float* hout = (l == 0) ? bufA : (l == 1) ? bufB : out;
        const bool relu = (l > 0);  // input of layers 1,2 is relu(prev)
        const float* root = roots + (size_t)l * D * D;
        const float* bias = biases + (size_t)l * D;

        // h_out = act(h) @ root + bias   (initializes every element, no memset)
        if (relu) gemm_kernel<true,  true><<<ggrid, 256, 0, stream>>>(h, root, bias, hout);
        else      gemm_kernel<false, true><<<ggrid, 256, 0, stream>>>(h, root, bias, hout);

        for (int r = 0; r < R; ++r) {
            const float* Wr = W + ((size_t)l * R + r) * (size_t)D * D;
            if (relu) gemm_kernel<true,  false><<<ggrid, 256, 0, stream>>>(h, Wr, nullptr, Ybuf);
            else      gemm_kernel<false, false><<<ggrid, 256, 0, stream>>>(h, Wr, nullptr, Ybuf);
            scatter_kernel<<<sgrid, 256, 0, stream>>>(Ybuf, src, dst, etyp, invp, hout, r);
        }
        h = hout;
    }
}

// Round 2
// 2182.466 us; speedup vs baseline: 2.6253x; 2.6253x over previous
//
#include <hip/hip_runtime.h>

#define NN 100000
#define NE 1600000
#define D  128
#define R  5
#define L  3
#define NR (NN * R)          // 500000 segments
#define NB1 489              // ceil(NR / 1024) scan blocks

// ============================================================================
// Prepass: build CSR sorted by (dst, relation).  Runs once per call (~60 µs).
// ============================================================================
__global__ __launch_bounds__(256) void count_kernel(const int* __restrict__ dst,
                                                    const int* __restrict__ et,
                                                    int* __restrict__ cnt) {
    int e = blockIdx.x * 256 + threadIdx.x;
    if (e < NE) atomicAdd(&cnt[dst[e] * R + et[e]], 1);
}

// 1024 items / block, 256 threads x 4.
__global__ __launch_bounds__(256) void scan1_kernel(const int* __restrict__ cnt,
                                                    int* __restrict__ pos,
                                                    int* __restrict__ bsum) {
    __shared__ int sh[256];
    const int b = blockIdx.x, t = threadIdx.x;
    const int base = b * 1024 + t * 4;
    int v[4], s = 0;
#pragma unroll
    for (int i = 0; i < 4; ++i) {
        v[i] = (base + i < NR) ? cnt[base + i] : 0;
        s += v[i];
    }
    sh[t] = s;
    __syncthreads();
    for (int off = 1; off < 256; off <<= 1) {
        int x = (t >= off) ? sh[t - off] : 0;
        __syncthreads();
        sh[t] += x;
        __syncthreads();
    }
    int run = sh[t] - s;               // exclusive within block
    if (t == 255) bsum[b] = sh[255];
#pragma unroll
    for (int i = 0; i < 4; ++i) {
        if (base + i < NR) pos[base + i] = run;
        run += v[i];
    }
}

__global__ __launch_bounds__(512) void scan2_kernel(const int* __restrict__ bsum,
                                                    int* __restrict__ boff) {
    __shared__ int sh[512];
    const int t = threadIdx.x;
    int v = (t < NB1) ? bsum[t] : 0;
    sh[t] = v;
    __syncthreads();
    for (int off = 1; off < 512; off <<= 1) {
        int x = (t >= off) ? sh[t - off] : 0;
        __syncthreads();
        sh[t] += x;
        __syncthreads();
    }
    if (t < NB1) boff[t] = sh[t] - v;  // exclusive
}

__global__ __launch_bounds__(256) void scan3_kernel(const int* __restrict__ pos,
                                                    const int* __restrict__ boff,
                                                    const int* __restrict__ cnt,
                                                    int* __restrict__ ptr,
                                                    int* __restrict__ fill,
                                                    float* __restrict__ inv) {
    int i = blockIdx.x * 256 + threadIdx.x;
    if (i < NR) {
        int p = pos[i] + boff[i >> 10];
        ptr[i] = p;
        fill[i] = p;
        int c = cnt[i];
        inv[i] = 1.0f / (float)(c > 0 ? c : 1);
    }
    if (i == 0) ptr[NR] = NE;
}

__global__ __launch_bounds__(256) void bucket_kernel(const int* __restrict__ src,
                                                     const int* __restrict__ dst,
                                                     const int* __restrict__ et,
                                                     int* __restrict__ fill,
                                                     int* __restrict__ ssrc) {
    int e = blockIdx.x * 256 + threadIdx.x;
    if (e < NE) {
        int p = atomicAdd(&fill[dst[e] * R + et[e]], 1);
        ssrc[p] = src[e];
    }
}

// ============================================================================
// Fused layer: per 128-node block, 6 phases (root + 5 relations):
//   phase: stage W (LDS) || gather-mean into A-tile (LDS, k-major, row-skew)
//          -> GEMM-accumulate acc[8][8] per thread.
// LDS: Ws 64 KB + Ms 70 KB = 134 KB -> 1 block/CU, 4 waves.
// Ms layout: MSADDR(k,r) = k*140 + r + 4*(r>>5)  (2-way banks on b128 reads).
// ============================================================================
#define MSROW(r) ((r) + 4 * ((r) >> 5))

template <int RELU>
__global__ __launch_bounds__(256, 1) void rgcn_layer(
    const float* __restrict__ h, const float* __restrict__ Wl,
    const float* __restrict__ root, const float* __restrict__ bias,
    const int* __restrict__ ptr, const int* __restrict__ ssrc,
    const float* __restrict__ inv, float* __restrict__ out) {
    __shared__ float Ws[128 * 128];
    __shared__ float Ms[128 * 140];

    const int tid  = threadIdx.x;
    const int row0 = blockIdx.x * 128;
    const int rgrp = (tid & 15) * 8;     // 8 output rows
    const int cgrp = (tid >> 4) * 8;     // 8 output cols
    const int aq   = tid & 3;            // k-quarter: 32 feats
    const int arow = tid >> 2;           // node within 64-node pass

    float acc[8][8];
#pragma unroll
    for (int i = 0; i < 8; ++i)
#pragma unroll
        for (int j = 0; j < 8; ++j) acc[i][j] = 0.0f;

#pragma unroll 1
    for (int ph = 0; ph <= R; ++ph) {
        __syncthreads();  // previous GEMM done reading Ws/Ms

        // ---- stage weights (64 KB, coalesced float4) ----
        {
            const float4* Bv = (const float4*)(ph == 0 ? root : Wl + (size_t)(ph - 1) * D * D);
            float4* Wv = (float4*)Ws;
#pragma unroll
            for (int i = 0; i < 16; ++i) Wv[tid + i * 256] = Bv[tid + i * 256];
        }

        // ---- build A-tile: 2 passes x 64 nodes, 4 threads/node x 32 feats ----
#pragma unroll 1
        for (int pass = 0; pass < 2; ++pass) {
            const int n = pass * 64 + arow;
            const int node = row0 + n;
            float4 v[8];
#pragma unroll
            for (int i = 0; i < 8; ++i) v[i] = make_float4(0.f, 0.f, 0.f, 0.f);

            if (node < NN) {
                if (ph == 0) {
                    const float4* hp = (const float4*)(h + (size_t)node * D + aq * 32);
#pragma unroll
                    for (int i = 0; i < 8; ++i) {
                        float4 t = hp[i];
                        if (RELU) {
                            t.x = fmaxf(t.x, 0.f); t.y = fmaxf(t.y, 0.f);
                            t.z = fmaxf(t.z, 0.f); t.w = fmaxf(t.w, 0.f);
                        }
                        v[i] = t;
                    }
                } else {
                    const int seg = node * R + (ph - 1);
                    const int e0 = ptr[seg], e1 = ptr[seg + 1];
                    for (int e = e0; e < e1; ++e) {
                        const int s = ssrc[e];
                        const float4* hp = (const float4*)(h + (size_t)s * D + aq * 32);
#pragma unroll
                        for (int i = 0; i < 8; ++i) {
                            float4 t = hp[i];
                            if (RELU) {
                                t.x = fmaxf(t.x, 0.f); t.y = fmaxf(t.y, 0.f);
                                t.z = fmaxf(t.z, 0.f); t.w = fmaxf(t.w, 0.f);
                            }
                            v[i].x += t.x; v[i].y += t.y; v[i].z += t.z; v[i].w += t.w;
                        }
                    }
                    const float sc = inv[seg];
#pragma unroll
                    for (int i = 0; i < 8; ++i) {
                        v[i].x *= sc; v[i].y *= sc; v[i].z *= sc; v[i].w *= sc;
                    }
                }
            }
            // store k-major (2-way bank pattern via pad-8-per-32k row placement)
            const int roff = MSROW(n);
#pragma unroll
            for (int i = 0; i < 8; ++i) {
                const int k = aq * 32 + i * 4;
                Ms[(k + 0) * 140 + roff] = v[i].x;
                Ms[(k + 1) * 140 + roff] = v[i].y;
                Ms[(k + 2) * 140 + roff] = v[i].z;
                Ms[(k + 3) * 140 + roff] = v[i].w;
            }
        }
        __syncthreads();

        // ---- GEMM: acc += A[128xk=128] * B[k=128x128] ----
        const int ra = MSROW(rgrp);      // rows rgrp..+7 stay in one 32-row group
#pragma unroll 4
        for (int k = 0; k < 128; ++k) {
            const float4 a0 = *(const float4*)&Ms[k * 140 + ra];
            const float4 a1 = *(const float4*)&Ms[k * 140 + ra + 4];
            const float4 b0 = *(const float4*)&Ws[k * 128 + cgrp];
            const float4 b1 = *(const float4*)&Ws[k * 128 + cgrp + 4];
            const float av[8] = {a0.x, a0.y, a0.z, a0.w, a1.x, a1.y, a1.z, a1.w};
            const float bv[8] = {b0.x, b0.y, b0.z, b0.w, b1.x, b1.y, b1.z, b1.w};
#pragma unroll
            for (int i = 0; i < 8; ++i)
#pragma unroll
                for (int j = 0; j < 8; ++j) acc[i][j] += av[i] * bv[j];
        }
    }

    // ---- epilogue: + bias, plain coalesced stores ----
    const float4 bc0 = *(const float4*)&bias[cgrp];
    const float4 bc1 = *(const float4*)&bias[cgrp + 4];
#pragma unroll
    for (int i = 0; i < 8; ++i) {
        const int row = row0 + rgrp + i;
        if (row < NN) {
            float4 o0 = make_float4(acc[i][0] + bc0.x, acc[i][1] + bc0.y,
                                    acc[i][2] + bc0.z, acc[i][3] + bc0.w);
            float4 o1 = make_float4(acc[i][4] + bc1.x, acc[i][5] + bc1.y,
                                    acc[i][6] + bc1.z, acc[i][7] + bc1.w);
            *(float4*)&out[(size_t)row * D + cgrp]     = o0;
            *(float4*)&out[(size_t)row * D + cgrp + 4] = o1;
        }
    }
}

// ============================================================================
extern "C" void kernel_launch(void* const* d_in, const int* in_sizes, int n_in,
                              void* d_out, int out_size, void* d_ws, size_t ws_size,
                              hipStream_t stream) {
    const float* x      = (const float*)d_in[0];
    const int*   eidx   = (const int*)d_in[1];
    const int*   etyp   = (const int*)d_in[2];
    const float* W      = (const float*)d_in[3];   // [L][R][D][D]
    const float* roots  = (const float*)d_in[4];   // [L][D][D]
    const float* biases = (const float*)d_in[5];   // [L][D]
    float*       out    = (float*)d_out;

    const int* src = eidx;
    const int* dst = eidx + NE;

    // workspace layout (~119 MB)
    float* bufA = (float*)d_ws;                    // N*D
    float* bufB = bufA + (size_t)NN * D;           // N*D
    int*   ptr  = (int*)(bufB + (size_t)NN * D);   // NR+1
    int*   fill = ptr + NR + 1;                    // NR
    float* invp = (float*)(fill + NR);             // NR
    int*   cnt  = (int*)(invp + NR);               // NR
    int*   pos  = cnt + NR;                        // NR
    int*   bsum = pos + NR;                        // 512
    int*   boff = bsum + 512;                      // 512
    int*   ssrc = boff + 512;                      // NE

    hipMemsetAsync(cnt, 0, sizeof(int) * (size_t)NR, stream);
    count_kernel<<<(NE + 255) / 256, 256, 0, stream>>>(dst, etyp, cnt);
    scan1_kernel<<<NB1, 256, 0, stream>>>(cnt, pos, bsum);
    scan2_kernel<<<1, 512, 0, stream>>>(bsum, boff);
    scan3_kernel<<<(NR + 255) / 256, 256, 0, stream>>>(pos, boff, cnt, ptr, fill, invp);
    bucket_kernel<<<(NE + 255) / 256, 256, 0, stream>>>(src, dst, etyp, fill, ssrc);

    const dim3 lgrid((NN + 127) / 128);
    rgcn_layer<0><<<lgrid, 256, 0, stream>>>(x,    W + 0 * (size_t)R * D * D,
                                             roots + 0 * (size_t)D * D, biases + 0 * D,
                                             ptr, ssrc, invp, bufA);
    rgcn_layer<1><<<lgrid, 256, 0, stream>>>(bufA, W + 1 * (size_t)R * D * D,
                                             roots + 1 * (size_t)D * D, biases + 1 * D,
                                             ptr, ssrc, invp, bufB);
    rgcn_layer<1><<<lgrid, 256, 0, stream>>>(bufB, W + 2 * (size_t)R * D * D,
                                             roots + 2 * (size_t)D * D, biases + 2 * D,
                                             ptr, ssrc, invp, out);
}

// Round 3
// 1339.778 us; speedup vs baseline: 4.2765x; 1.6290x over previous
//
#include <hip/hip_runtime.h>

#define NN 100000
#define NE 1600000
#define D  128
#define R  5
#define L  3
#define NR (NN * R)          // 500000 segments
#define NB1 489              // ceil(NR / 1024)
#define PADK 136             // bf16 per LDS A-row (128 + 8 pad = +16B)

typedef __attribute__((ext_vector_type(8))) short bf16x8;
typedef __attribute__((ext_vector_type(4))) float f32x4;

// ============================================================================
// Prepass: CSR keyed by seg = rel*NN + dst  (per-relation node ranges are
// contiguous -> phase r of the layer kernel reads one contiguous ptr range).
// ============================================================================
__global__ __launch_bounds__(256) void count_kernel(const int* __restrict__ dst,
                                                    const int* __restrict__ et,
                                                    int* __restrict__ cnt) {
    int e = blockIdx.x * 256 + threadIdx.x;
    if (e < NE) atomicAdd(&cnt[et[e] * NN + dst[e]], 1);
}

__global__ __launch_bounds__(256) void scan1_kernel(const int* __restrict__ cnt,
                                                    int* __restrict__ pos,
                                                    int* __restrict__ bsum) {
    __shared__ int sh[256];
    const int b = blockIdx.x, t = threadIdx.x;
    const int base = b * 1024 + t * 4;
    int v[4], s = 0;
#pragma unroll
    for (int i = 0; i < 4; ++i) {
        v[i] = (base + i < NR) ? cnt[base + i] : 0;
        s += v[i];
    }
    sh[t] = s;
    __syncthreads();
    for (int off = 1; off < 256; off <<= 1) {
        int x = (t >= off) ? sh[t - off] : 0;
        __syncthreads();
        sh[t] += x;
        __syncthreads();
    }
    int run = sh[t] - s;
    if (t == 255) bsum[b] = sh[255];
#pragma unroll
    for (int i = 0; i < 4; ++i) {
        if (base + i < NR) pos[base + i] = run;
        run += v[i];
    }
}

__global__ __launch_bounds__(512) void scan2_kernel(const int* __restrict__ bsum,
                                                    int* __restrict__ boff) {
    __shared__ int sh[512];
    const int t = threadIdx.x;
    int v = (t < NB1) ? bsum[t] : 0;
    sh[t] = v;
    __syncthreads();
    for (int off = 1; off < 512; off <<= 1) {
        int x = (t >= off) ? sh[t - off] : 0;
        __syncthreads();
        sh[t] += x;
        __syncthreads();
    }
    if (t < NB1) boff[t] = sh[t] - v;
}

__global__ __launch_bounds__(256) void scan3_kernel(const int* __restrict__ pos,
                                                    const int* __restrict__ boff,
                                                    const int* __restrict__ cnt,
                                                    int* __restrict__ ptr,
                                                    int* __restrict__ fill,
                                                    float* __restrict__ inv) {
    int i = blockIdx.x * 256 + threadIdx.x;
    if (i < NR) {
        int p = pos[i] + boff[i >> 10];
        ptr[i] = p;
        fill[i] = p;
        int c = cnt[i];
        inv[i] = 1.0f / (float)(c > 0 ? c : 1);
    }
    if (i == 0) ptr[NR] = NE;
}

__global__ __launch_bounds__(256) void bucket_kernel(const int* __restrict__ src,
                                                     const int* __restrict__ dst,
                                                     const int* __restrict__ et,
                                                     int* __restrict__ fill,
                                                     int* __restrict__ ssrc) {
    int e = blockIdx.x * 256 + threadIdx.x;
    if (e < NE) {
        int p = atomicAdd(&fill[et[e] * NN + dst[e]], 1);
        ssrc[p] = src[e];
    }
}

// ============================================================================
// Weight prep (once per call): transpose + exact bf16 hi/lo split.
// Wt[mat][dc][dk] with mat = l*6 + ph (ph 0 = root, 1..5 = relations).
// B-fragment of mfma_16x16x32 wants contiguous k for a fixed col -> [dc][dk].
// ============================================================================
__device__ __forceinline__ void split2(float f0, float f1, uint& hw, uint& lw) {
    uint b0 = __builtin_bit_cast(uint, f0), b1 = __builtin_bit_cast(uint, f1);
    uint h0 = b0 >> 16, h1 = b1 >> 16;
    float r0 = f0 - __builtin_bit_cast(float, h0 << 16);
    float r1 = f1 - __builtin_bit_cast(float, h1 << 16);
    hw = h0 | (h1 << 16);
    lw = (__builtin_bit_cast(uint, r0) >> 16) | (__builtin_bit_cast(uint, r1) & 0xFFFF0000u);
}

__global__ __launch_bounds__(256) void wprep_kernel(const float* __restrict__ W,
                                                    const float* __restrict__ roots,
                                                    ushort* __restrict__ WtH,
                                                    ushort* __restrict__ WtL) {
    const int mat = blockIdx.x;        // 0..17
    const int l = mat / 6, ph = mat % 6;
    const float* S = (ph == 0) ? roots + (size_t)l * D * D
                               : W + ((size_t)l * R + (ph - 1)) * D * D;
    const int t = threadIdx.x;
    const int dc = t & 127;
    const int half = t >> 7;           // dk 0..63 / 64..127
    uint* oh = (uint*)(WtH + ((size_t)mat * D + dc) * D) + half * 32;
    uint* ol = (uint*)(WtL + ((size_t)mat * D + dc) * D) + half * 32;
#pragma unroll 4
    for (int j = 0; j < 32; ++j) {
        int dk = half * 64 + j * 2;
        uint hw, lw;
        split2(S[(size_t)dk * D + dc], S[(size_t)(dk + 1) * D + dc], hw, lw);
        oh[j] = hw;
        ol[j] = lw;
    }
}

// ============================================================================
// Fused layer: 128 nodes x 128 cols per block, 512 threads (8 waves).
// 6 phases (root + 5 relations): gather-mean into split-bf16 LDS A-tile,
// then 16x16x32 bf16 MFMA with 3-term split (Ah*Bh + Al*Bh + Ah*Bl ~ fp32).
// LDS 2x128x136x2B = 68 KB -> 2 blocks/CU (16 waves/CU) for gather latency.
// Wave w: (wr=w&3, wc=w>>2) owns a 32-row x 64-col output sub-tile.
// ============================================================================
template <int RELU>
__global__ __launch_bounds__(512, 4) void rgcn_layer(
    const float* __restrict__ h, const ushort* __restrict__ WtH,
    const ushort* __restrict__ WtL, const float* __restrict__ bias,
    const int* __restrict__ ptr, const int* __restrict__ ssrc,
    const float* __restrict__ inv, float* __restrict__ out) {
    __shared__ ushort Ahi[128 * PADK];
    __shared__ ushort Alo[128 * PADK];

    const int tid   = threadIdx.x;
    const int row0  = blockIdx.x * 128;
    const int lane  = tid & 63;
    const int wv    = tid >> 6;
    const int wr    = wv & 3;          // 32-row group
    const int wc    = wv >> 2;         // 64-col group
    const int anode = tid >> 2;        // 0..127: node this thread aggregates
    const int aq    = tid & 3;         // 32-feature quarter
    const int lr    = lane & 15;
    const int lg    = lane >> 4;

    f32x4 acc[2][4];
#pragma unroll
    for (int m = 0; m < 2; ++m)
#pragma unroll
        for (int n = 0; n < 4; ++n) acc[m][n] = (f32x4){0.f, 0.f, 0.f, 0.f};

#pragma unroll 1
    for (int ph = 0; ph < 6; ++ph) {
        __syncthreads();   // previous phase done reading the A-tile

        // ---- gather-mean 32 features of node `anode` into v[8] ----
        float4 v[8];
#pragma unroll
        for (int i = 0; i < 8; ++i) v[i] = make_float4(0.f, 0.f, 0.f, 0.f);

        const int node = row0 + anode;
        if (node < NN) {
            if (ph == 0) {
                const float4* hp = (const float4*)(h + (size_t)node * D + aq * 32);
#pragma unroll
                for (int i = 0; i < 8; ++i) {
                    float4 t4 = hp[i];
                    if (RELU) {
                        t4.x = fmaxf(t4.x, 0.f); t4.y = fmaxf(t4.y, 0.f);
                        t4.z = fmaxf(t4.z, 0.f); t4.w = fmaxf(t4.w, 0.f);
                    }
                    v[i] = t4;
                }
            } else {
                const int seg = (ph - 1) * NN + node;
                const int e0 = ptr[seg], e1 = ptr[seg + 1];
                for (int e = e0; e < e1; ++e) {
                    const float4* hp = (const float4*)(h + (size_t)ssrc[e] * D + aq * 32);
#pragma unroll
                    for (int i = 0; i < 8; ++i) {
                        float4 t4 = hp[i];
                        if (RELU) {
                            t4.x = fmaxf(t4.x, 0.f); t4.y = fmaxf(t4.y, 0.f);
                            t4.z = fmaxf(t4.z, 0.f); t4.w = fmaxf(t4.w, 0.f);
                        }
                        v[i].x += t4.x; v[i].y += t4.y; v[i].z += t4.z; v[i].w += t4.w;
                    }
                }
                const float sc = inv[seg];
#pragma unroll
                for (int i = 0; i < 8; ++i) {
                    v[i].x *= sc; v[i].y *= sc; v[i].z *= sc; v[i].w *= sc;
                }
            }
        }

        // ---- exact split to bf16 hi/lo, write LDS (b128, 2-way banks) ----
        const int base = anode * PADK + aq * 32;   // ushort index, 16B-aligned
#pragma unroll
        for (int g = 0; g < 4; ++g) {
            uint4 H, Lo;
            split2(v[2 * g].x,     v[2 * g].y,     H.x, Lo.x);
            split2(v[2 * g].z,     v[2 * g].w,     H.y, Lo.y);
            split2(v[2 * g + 1].x, v[2 * g + 1].y, H.z, Lo.z);
            split2(v[2 * g + 1].z, v[2 * g + 1].w, H.w, Lo.w);
            ((uint4*)&Ahi[base])[g] = H;
            ((uint4*)&Alo[base])[g] = Lo;
        }
        __syncthreads();

        // ---- MFMA: acc += A[128x128] * Wt[ph]^ (3-term split) ----
        const ushort* BH = WtH + (size_t)ph * D * D;
        const ushort* BL = WtL + (size_t)ph * D * D;
        const int arow = wr * 32 + lr;
#pragma unroll
        for (int ks = 0; ks < 4; ++ks) {
            const int ak = ks * 32 + lg * 8;
            const bf16x8 a0h = *(const bf16x8*)&Ahi[arow * PADK + ak];
            const bf16x8 a1h = *(const bf16x8*)&Ahi[(arow + 16) * PADK + ak];
            const bf16x8 a0l = *(const bf16x8*)&Alo[arow * PADK + ak];
            const bf16x8 a1l = *(const bf16x8*)&Alo[(arow + 16) * PADK + ak];
#pragma unroll
            for (int n = 0; n < 4; ++n) {
                const int bc = wc * 64 + n * 16 + lr;
                const bf16x8 bh = *(const bf16x8*)&BH[(size_t)bc * D + ak];
                const bf16x8 bl = *(const bf16x8*)&BL[(size_t)bc * D + ak];
                acc[0][n] = __builtin_amdgcn_mfma_f32_16x16x32_bf16(a0h, bh, acc[0][n], 0, 0, 0);
                acc[1][n] = __builtin_amdgcn_mfma_f32_16x16x32_bf16(a1h, bh, acc[1][n], 0, 0, 0);
                acc[0][n] = __builtin_amdgcn_mfma_f32_16x16x32_bf16(a0l, bh, acc[0][n], 0, 0, 0);
                acc[1][n] = __builtin_amdgcn_mfma_f32_16x16x32_bf16(a1l, bh, acc[1][n], 0, 0, 0);
                acc[0][n] = __builtin_amdgcn_mfma_f32_16x16x32_bf16(a0h, bl, acc[0][n], 0, 0, 0);
                acc[1][n] = __builtin_amdgcn_mfma_f32_16x16x32_bf16(a1h, bl, acc[1][n], 0, 0, 0);
            }
        }
    }

    // ---- epilogue: bias + store (C/D: col=lane&15, row=(lane>>4)*4+reg) ----
    const int c0 = wc * 64;
#pragma unroll
    for (int m = 0; m < 2; ++m) {
        const int rbase = row0 + wr * 32 + m * 16 + lg * 4;
#pragma unroll
        for (int n = 0; n < 4; ++n) {
            const int col = c0 + n * 16 + lr;
            const float b = bias[col];
#pragma unroll
            for (int vi = 0; vi < 4; ++vi) {
                const int row = rbase + vi;
                if (row < NN) out[(size_t)row * D + col] = acc[m][n][vi] + b;
            }
        }
    }
}

// ============================================================================
extern "C" void kernel_launch(void* const* d_in, const int* in_sizes, int n_in,
                              void* d_out, int out_size, void* d_ws, size_t ws_size,
                              hipStream_t stream) {
    const float* x      = (const float*)d_in[0];
    const int*   eidx   = (const int*)d_in[1];
    const int*   etyp   = (const int*)d_in[2];
    const float* W      = (const float*)d_in[3];   // [L][R][D][D]
    const float* roots  = (const float*)d_in[4];   // [L][D][D]
    const float* biases = (const float*)d_in[5];   // [L][D]
    float*       out    = (float*)d_out;

    const int* src = eidx;
    const int* dst = eidx + NE;

    // workspace layout (~122 MB)
    float*  bufA = (float*)d_ws;                     // N*D
    float*  bufB = bufA + (size_t)NN * D;            // N*D
    int*    ptr  = (int*)(bufB + (size_t)NN * D);    // NR+1
    int*    fill = ptr + NR + 1;                     // NR
    float*  invp = (float*)(fill + NR);              // NR
    int*    cnt  = (int*)(invp + NR);                // NR
    int*    pos  = cnt + NR;                         // NR
    int*    bsum = pos + NR;                         // 512
    int*    boff = bsum + 512;                       // 512
    int*    ssrc = boff + 512;                       // NE
    ushort* WtH  = (ushort*)(ssrc + NE);             // 18*128*128
    ushort* WtL  = WtH + (size_t)L * 6 * D * D;      // 18*128*128

    hipMemsetAsync(cnt, 0, sizeof(int) * (size_t)NR, stream);
    count_kernel<<<(NE + 255) / 256, 256, 0, stream>>>(dst, etyp, cnt);
    scan1_kernel<<<NB1, 256, 0, stream>>>(cnt, pos, bsum);
    scan2_kernel<<<1, 512, 0, stream>>>(bsum, boff);
    scan3_kernel<<<(NR + 255) / 256, 256, 0, stream>>>(pos, boff, cnt, ptr, fill, invp);
    bucket_kernel<<<(NE + 255) / 256, 256, 0, stream>>>(src, dst, etyp, fill, ssrc);
    wprep_kernel<<<L * 6, 256, 0, stream>>>(W, roots, WtH, WtL);

    const dim3 lgrid((NN + 127) / 128);
    rgcn_layer<0><<<lgrid, 512, 0, stream>>>(x,    WtH + 0 * (size_t)6 * D * D,
                                             WtL + 0 * (size_t)6 * D * D, biases + 0 * D,
                                             ptr, ssrc, invp, bufA);
    rgcn_layer<1><<<lgrid, 512, 0, stream>>>(bufA, WtH + 1 * (size_t)6 * D * D,
                                             WtL + 1 * (size_t)6 * D * D, biases + 1 * D,
                                             ptr, ssrc, invp, bufB);
    rgcn_layer<1><<<lgrid, 512, 0, stream>>>(bufB, WtH + 2 * (size_t)6 * D * D,
                                             WtL + 2 * (size_t)6 * D * D, biases + 2 * D,
                                             ptr, ssrc, invp, out);
}

// Round 4
// 1073.353 us; speedup vs baseline: 5.3380x; 1.2482x over previous
//
#include <hip/hip_runtime.h>

#define NN 100000
#define NE 1600000
#define D  128
#define R  5
#define L  3
#define NR (NN * R)          // 500000 segments
#define NB1 489              // ceil(NR / 1024)
#define PADK 136             // bf16 per LDS A-row (128 + 8 pad = +16B)
#define TR 64                // tile rows (nodes per block)

typedef __attribute__((ext_vector_type(8))) short bf16x8;
typedef __attribute__((ext_vector_type(4))) float f32x4;

// ============================================================================
// Prepass: CSR keyed by seg = rel*NN + dst.
// ============================================================================
__global__ __launch_bounds__(256) void count_kernel(const int* __restrict__ dst,
                                                    const int* __restrict__ et,
                                                    int* __restrict__ cnt) {
    int e = blockIdx.x * 256 + threadIdx.x;
    if (e < NE) atomicAdd(&cnt[et[e] * NN + dst[e]], 1);
}

__global__ __launch_bounds__(256) void scan1_kernel(const int* __restrict__ cnt,
                                                    int* __restrict__ pos,
                                                    int* __restrict__ bsum) {
    __shared__ int sh[256];
    const int b = blockIdx.x, t = threadIdx.x;
    const int base = b * 1024 + t * 4;
    int v[4], s = 0;
#pragma unroll
    for (int i = 0; i < 4; ++i) {
        v[i] = (base + i < NR) ? cnt[base + i] : 0;
        s += v[i];
    }
    sh[t] = s;
    __syncthreads();
    for (int off = 1; off < 256; off <<= 1) {
        int x = (t >= off) ? sh[t - off] : 0;
        __syncthreads();
        sh[t] += x;
        __syncthreads();
    }
    int run = sh[t] - s;
    if (t == 255) bsum[b] = sh[255];
#pragma unroll
    for (int i = 0; i < 4; ++i) {
        if (base + i < NR) pos[base + i] = run;
        run += v[i];
    }
}

__global__ __launch_bounds__(512) void scan2_kernel(const int* __restrict__ bsum,
                                                    int* __restrict__ boff) {
    __shared__ int sh[512];
    const int t = threadIdx.x;
    int v = (t < NB1) ? bsum[t] : 0;
    sh[t] = v;
    __syncthreads();
    for (int off = 1; off < 512; off <<= 1) {
        int x = (t >= off) ? sh[t - off] : 0;
        __syncthreads();
        sh[t] += x;
        __syncthreads();
    }
    if (t < NB1) boff[t] = sh[t] - v;
}

__global__ __launch_bounds__(256) void scan3_kernel(const int* __restrict__ pos,
                                                    const int* __restrict__ boff,
                                                    const int* __restrict__ cnt,
                                                    int* __restrict__ ptr,
                                                    int* __restrict__ fill,
                                                    float* __restrict__ inv) {
    int i = blockIdx.x * 256 + threadIdx.x;
    if (i < NR) {
        int p = pos[i] + boff[i >> 10];
        ptr[i] = p;
        fill[i] = p;
        int c = cnt[i];
        inv[i] = 1.0f / (float)(c > 0 ? c : 1);
    }
    if (i == 0) ptr[NR] = NE;
}

__global__ __launch_bounds__(256) void bucket_kernel(const int* __restrict__ src,
                                                     const int* __restrict__ dst,
                                                     const int* __restrict__ et,
                                                     int* __restrict__ fill,
                                                     int* __restrict__ ssrc) {
    int e = blockIdx.x * 256 + threadIdx.x;
    if (e < NE) {
        int p = atomicAdd(&fill[et[e] * NN + dst[e]], 1);
        ssrc[p] = src[e];
    }
}

// ============================================================================
// Weight prep: transpose + exact bf16 hi/lo split. Wt[mat][col][k].
// ============================================================================
__device__ __forceinline__ void split2(float f0, float f1, uint& hw, uint& lw) {
    uint b0 = __builtin_bit_cast(uint, f0), b1 = __builtin_bit_cast(uint, f1);
    uint h0 = b0 >> 16, h1 = b1 >> 16;
    float r0 = f0 - __builtin_bit_cast(float, h0 << 16);
    float r1 = f1 - __builtin_bit_cast(float, h1 << 16);
    hw = h0 | (h1 << 16);
    lw = (__builtin_bit_cast(uint, r0) >> 16) | (__builtin_bit_cast(uint, r1) & 0xFFFF0000u);
}

__global__ __launch_bounds__(256) void wprep_kernel(const float* __restrict__ W,
                                                    const float* __restrict__ roots,
                                                    ushort* __restrict__ WtH,
                                                    ushort* __restrict__ WtL) {
    const int mat = blockIdx.x;        // 0..17
    const int l = mat / 6, ph = mat % 6;
    const float* S = (ph == 0) ? roots + (size_t)l * D * D
                               : W + ((size_t)l * R + (ph - 1)) * D * D;
    const int t = threadIdx.x;
    const int dc = t & 127;
    const int half = t >> 7;
    uint* oh = (uint*)(WtH + ((size_t)mat * D + dc) * D) + half * 32;
    uint* ol = (uint*)(WtL + ((size_t)mat * D + dc) * D) + half * 32;
#pragma unroll 4
    for (int j = 0; j < 32; ++j) {
        int dk = half * 64 + j * 2;
        uint hw, lw;
        split2(S[(size_t)dk * D + dc], S[(size_t)(dk + 1) * D + dc], hw, lw);
        oh[j] = hw;
        ol[j] = lw;
    }
}

// ============================================================================
// Fused layer: 64 nodes x 128 cols per block, 512 threads (8 waves).
// LDS 34 KB -> 4 blocks/CU; launch_bounds(512,8) caps VGPR at 64
// -> 32 waves/CU for gather latency hiding.
// Wave wv: (wr=wv&1, wc=wv>>1) owns a 32-row x 32-col output sub-tile.
// Gather: 8 threads/node, 16 floats each (4 float4 in flight/thread).
// ============================================================================
template <int RELU>
__global__ __launch_bounds__(512, 8) void rgcn_layer(
    const float* __restrict__ h, const ushort* __restrict__ WtH,
    const ushort* __restrict__ WtL, const float* __restrict__ bias,
    const int* __restrict__ ptr, const int* __restrict__ ssrc,
    const float* __restrict__ inv, float* __restrict__ out) {
    __shared__ ushort Ahi[TR * PADK];
    __shared__ ushort Alo[TR * PADK];

    const int tid   = threadIdx.x;
    const int row0  = blockIdx.x * TR;
    const int lane  = tid & 63;
    const int wv    = tid >> 6;
    const int wr    = wv & 1;          // 32-row group
    const int wc    = wv >> 1;         // 32-col group
    const int anode = tid >> 3;        // 0..63
    const int q     = tid & 3;         // unused placeholder (kept simple below)
    const int aq    = tid & 7;         // 16-float chunk of the row
    const int lr    = lane & 15;
    const int lg    = lane >> 4;
    (void)q;

    f32x4 acc[2][2];
#pragma unroll
    for (int m = 0; m < 2; ++m)
#pragma unroll
        for (int n = 0; n < 2; ++n) acc[m][n] = (f32x4){0.f, 0.f, 0.f, 0.f};

#pragma unroll 1
    for (int ph = 0; ph < 6; ++ph) {
        __syncthreads();   // previous phase done reading the A-tile

        // ---- gather-mean 16 features of node `anode` ----
        float4 v[4];
#pragma unroll
        for (int i = 0; i < 4; ++i) v[i] = make_float4(0.f, 0.f, 0.f, 0.f);

        const int node = row0 + anode;
        if (node < NN) {
            if (ph == 0) {
                const float4* hp = (const float4*)(h + (size_t)node * D + aq * 16);
#pragma unroll
                for (int i = 0; i < 4; ++i) {
                    float4 t4 = hp[i];
                    if (RELU) {
                        t4.x = fmaxf(t4.x, 0.f); t4.y = fmaxf(t4.y, 0.f);
                        t4.z = fmaxf(t4.z, 0.f); t4.w = fmaxf(t4.w, 0.f);
                    }
                    v[i] = t4;
                }
            } else {
                const int seg = (ph - 1) * NN + node;
                const int e0 = ptr[seg], e1 = ptr[seg + 1];
                for (int e = e0; e < e1; ++e) {
                    const float4* hp = (const float4*)(h + (size_t)ssrc[e] * D + aq * 16);
                    float4 t0 = hp[0], t1 = hp[1], t2 = hp[2], t3 = hp[3];
                    if (RELU) {
                        t0.x = fmaxf(t0.x, 0.f); t0.y = fmaxf(t0.y, 0.f);
                        t0.z = fmaxf(t0.z, 0.f); t0.w = fmaxf(t0.w, 0.f);
                        t1.x = fmaxf(t1.x, 0.f); t1.y = fmaxf(t1.y, 0.f);
                        t1.z = fmaxf(t1.z, 0.f); t1.w = fmaxf(t1.w, 0.f);
                        t2.x = fmaxf(t2.x, 0.f); t2.y = fmaxf(t2.y, 0.f);
                        t2.z = fmaxf(t2.z, 0.f); t2.w = fmaxf(t2.w, 0.f);
                        t3.x = fmaxf(t3.x, 0.f); t3.y = fmaxf(t3.y, 0.f);
                        t3.z = fmaxf(t3.z, 0.f); t3.w = fmaxf(t3.w, 0.f);
                    }
                    v[0].x += t0.x; v[0].y += t0.y; v[0].z += t0.z; v[0].w += t0.w;
                    v[1].x += t1.x; v[1].y += t1.y; v[1].z += t1.z; v[1].w += t1.w;
                    v[2].x += t2.x; v[2].y += t2.y; v[2].z += t2.z; v[2].w += t2.w;
                    v[3].x += t3.x; v[3].y += t3.y; v[3].z += t3.z; v[3].w += t3.w;
                }
                const float sc = inv[seg];
#pragma unroll
                for (int i = 0; i < 4; ++i) {
                    v[i].x *= sc; v[i].y *= sc; v[i].z *= sc; v[i].w *= sc;
                }
            }
        }

        // ---- exact split to bf16 hi/lo, write LDS (b128) ----
        const int base = anode * PADK + aq * 16;   // ushort index, 16B-aligned
#pragma unroll
        for (int g = 0; g < 2; ++g) {
            uint4 H, Lo;
            split2(v[2 * g].x,     v[2 * g].y,     H.x, Lo.x);
            split2(v[2 * g].z,     v[2 * g].w,     H.y, Lo.y);
            split2(v[2 * g + 1].x, v[2 * g + 1].y, H.z, Lo.z);
            split2(v[2 * g + 1].z, v[2 * g + 1].w, H.w, Lo.w);
            ((uint4*)&Ahi[base])[g] = H;
            ((uint4*)&Alo[base])[g] = Lo;
        }
        __syncthreads();

        // ---- MFMA: acc += A[64x128] * Wt[ph]^ (3-term split) ----
        const ushort* BH = WtH + (size_t)ph * D * D;
        const ushort* BL = WtL + (size_t)ph * D * D;
        const int arow = wr * 32 + lr;
#pragma unroll
        for (int ks = 0; ks < 4; ++ks) {
            const int ak = ks * 32 + lg * 8;
            const bf16x8 a0h = *(const bf16x8*)&Ahi[arow * PADK + ak];
            const bf16x8 a1h = *(const bf16x8*)&Ahi[(arow + 16) * PADK + ak];
            const bf16x8 a0l = *(const bf16x8*)&Alo[arow * PADK + ak];
            const bf16x8 a1l = *(const bf16x8*)&Alo[(arow + 16) * PADK + ak];
#pragma unroll
            for (int n = 0; n < 2; ++n) {
                const int bc = wc * 32 + n * 16 + lr;
                const bf16x8 bh = *(const bf16x8*)&BH[(size_t)bc * D + ak];
                const bf16x8 bl = *(const bf16x8*)&BL[(size_t)bc * D + ak];
                acc[0][n] = __builtin_amdgcn_mfma_f32_16x16x32_bf16(a0h, bh, acc[0][n], 0, 0, 0);
                acc[1][n] = __builtin_amdgcn_mfma_f32_16x16x32_bf16(a1h, bh, acc[1][n], 0, 0, 0);
                acc[0][n] = __builtin_amdgcn_mfma_f32_16x16x32_bf16(a0l, bh, acc[0][n], 0, 0, 0);
                acc[1][n] = __builtin_amdgcn_mfma_f32_16x16x32_bf16(a1l, bh, acc[1][n], 0, 0, 0);
                acc[0][n] = __builtin_amdgcn_mfma_f32_16x16x32_bf16(a0h, bl, acc[0][n], 0, 0, 0);
                acc[1][n] = __builtin_amdgcn_mfma_f32_16x16x32_bf16(a1h, bl, acc[1][n], 0, 0, 0);
            }
        }
    }

    // ---- epilogue: bias + store (C/D: col=lane&15, row=(lane>>4)*4+reg) ----
#pragma unroll
    for (int m = 0; m < 2; ++m) {
        const int rbase = row0 + wr * 32 + m * 16 + lg * 4;
#pragma unroll
        for (int n = 0; n < 2; ++n) {
            const int col = wc * 32 + n * 16 + lr;
            const float b = bias[col];
#pragma unroll
            for (int vi = 0; vi < 4; ++vi) {
                const int row = rbase + vi;
                if (row < NN) out[(size_t)row * D + col] = acc[m][n][vi] + b;
            }
        }
    }
}

// ============================================================================
extern "C" void kernel_launch(void* const* d_in, const int* in_sizes, int n_in,
                              void* d_out, int out_size, void* d_ws, size_t ws_size,
                              hipStream_t stream) {
    const float* x      = (const float*)d_in[0];
    const int*   eidx   = (const int*)d_in[1];
    const int*   etyp   = (const int*)d_in[2];
    const float* W      = (const float*)d_in[3];   // [L][R][D][D]
    const float* roots  = (const float*)d_in[4];   // [L][D][D]
    const float* biases = (const float*)d_in[5];   // [L][D]
    float*       out    = (float*)d_out;

    const int* src = eidx;
    const int* dst = eidx + NE;

    // workspace layout (~122 MB)
    float*  bufA = (float*)d_ws;                     // N*D
    float*  bufB = bufA + (size_t)NN * D;            // N*D
    int*    ptr  = (int*)(bufB + (size_t)NN * D);    // NR+1
    int*    fill = ptr + NR + 1;                     // NR
    float*  invp = (float*)(fill + NR);              // NR
    int*    cnt  = (int*)(invp + NR);                // NR
    int*    pos  = cnt + NR;                         // NR
    int*    bsum = pos + NR;                         // 512
    int*    boff = bsum + 512;                       // 512
    int*    ssrc = boff + 512;                       // NE
    ushort* WtH  = (ushort*)(ssrc + NE);             // 18*128*128
    ushort* WtL  = WtH + (size_t)L * 6 * D * D;      // 18*128*128

    hipMemsetAsync(cnt, 0, sizeof(int) * (size_t)NR, stream);
    count_kernel<<<(NE + 255) / 256, 256, 0, stream>>>(dst, etyp, cnt);
    scan1_kernel<<<NB1, 256, 0, stream>>>(cnt, pos, bsum);
    scan2_kernel<<<1, 512, 0, stream>>>(bsum, boff);
    scan3_kernel<<<(NR + 255) / 256, 256, 0, stream>>>(pos, boff, cnt, ptr, fill, invp);
    bucket_kernel<<<(NE + 255) / 256, 256, 0, stream>>>(src, dst, etyp, fill, ssrc);
    wprep_kernel<<<L * 6, 256, 0, stream>>>(W, roots, WtH, WtL);

    const dim3 lgrid((NN + TR - 1) / TR);
    rgcn_layer<0><<<lgrid, 512, 0, stream>>>(x,    WtH + 0 * (size_t)6 * D * D,
                                             WtL + 0 * (size_t)6 * D * D, biases + 0 * D,
                                             ptr, ssrc, invp, bufA);
    rgcn_layer<1><<<lgrid, 512, 0, stream>>>(bufA, WtH + 1 * (size_t)6 * D * D,
                                             WtL + 1 * (size_t)6 * D * D, biases + 1 * D,
                                             ptr, ssrc, invp, bufB);
    rgcn_layer<1><<<lgrid, 512, 0, stream>>>(bufB, WtH + 2 * (size_t)6 * D * D,
                                             WtL + 2 * (size_t)6 * D * D, biases + 2 * D,
                                             ptr, ssrc, invp, out);
}